// Round 7
// baseline (101.780 us; speedup 1.0000x reference)
//
#include <hip/hip_runtime.h>
#include <math.h>

#define B_ 8
#define C_ 3
#define HW_ 512
#define P_ 128
#define S_ 64
#define K_ 31
#define NZ_ 15
#define HID_ 64
#define NPOS_ 49   // 7x7 patch positions
#define BN_ (B_*NPOS_)

#define LSTRIDE_ 168   // bf16 elems/row; 336 B = 21 x 16B blocks; 21 mod 8 = 5 (odd) -> conflict-free
#define TROWS_ 160     // 128 + 30 halo + 2 spare (rows 158,159 zero)
#define FRAG_U32_ 256  // one B fragment = 64 lanes x 16 B = 256 uints
#define NSTEP_ 16      // 16 row-pair steps cover j = 0..31 (row 31 masked to zero)
#define BPOS_U32_ (NSTEP_ * 3 * FRAG_U32_)  // 12288 uints per patch position

typedef __attribute__((ext_vector_type(8))) short bf16x8;
typedef __attribute__((ext_vector_type(4))) float f32x4;

__device__ __forceinline__ float hann128(int p) {
    return 0.5f - 0.5f * cosf(6.283185307179586f * (float)p / 128.0f);
}

__device__ __forceinline__ unsigned short bf16_rne(float f) {
    union { float f; unsigned int u; } v; v.f = f;
    unsigned int r = v.u + 0x7fffu + ((v.u >> 16) & 1u);
    return (unsigned short)(r >> 16);
}

__device__ __forceinline__ float bf16_to_f(unsigned int bits16) {
    union { unsigned int u; float f; } v; v.u = bits16 << 16;
    return v.f;
}

// ---------------------------------------------------------------------------
// Kernel 1: MLP + pupil + 31x31 DFT -> normalized flipped kernel -> row-pair
// B-fragment precompute. One block per patch position (49 blocks).
// Fragment (s, c): logical k in [0,32): jrow = 2s + (k>=16),
//   B_c[k][n] = kf[jrow, 16c + (k&15) - n] if valid else 0.
// Lane labeling (matches conv A reads, empirically validated r4/r5/r6):
//   lane l: n = l&15, k = (l>>4)*8 + e, e = 0..7.
// ---------------------------------------------------------------------------
__global__ __launch_bounds__(256) void psf_kernel(
    const float* __restrict__ w1, const float* __restrict__ b1,
    const float* __restrict__ w2, const float* __restrict__ b2,
    const float* __restrict__ w3, const float* __restrict__ b3,
    const float* __restrict__ basis, unsigned int* __restrict__ bfrags)
{
    __shared__ float h1[HID_], h2[HID_], coef[NZ_];
    __shared__ float pupR[961], pupI[961], tR[961], tI[961];
    __shared__ float rootR[31], rootI[31];
    __shared__ float red[256];
    int n = blockIdx.x;
    int nh = n / 7, nw = n % 7;
    int tid = threadIdx.x;
    float cy = (float)(nh * S_ + P_ / 2) * (2.0f / (float)HW_) - 1.0f;
    float cx = (float)(nw * S_ + P_ / 2) * (2.0f / (float)HW_) - 1.0f;

    if (tid < HID_) h1[tid] = fmaxf(0.0f, cy * w1[tid] + cx * w1[HID_ + tid] + b1[tid]);
    if (tid < 31) {
        float ang = -6.283185307179586f * (float)tid / 31.0f;
        rootR[tid] = cosf(ang);
        rootI[tid] = sinf(ang);
    }
    __syncthreads();
    if (tid < HID_) {
        float s = b2[tid];
        for (int k = 0; k < HID_; ++k) s = fmaf(h1[k], w2[k * HID_ + tid], s);
        h2[tid] = fmaxf(0.0f, s);
    }
    __syncthreads();
    if (tid < NZ_) {
        float s = b3[tid];
        for (int k = 0; k < HID_; ++k) s = fmaf(h2[k], w3[k * NZ_ + tid], s);
        coef[tid] = s;
    }
    __syncthreads();

    for (int idx = tid; idx < 961; idx += 256) {
        int h = idx / 31, w = idx % 31;
        float ph = 0.0f;
        for (int z = 0; z < NZ_; ++z) ph = fmaf(coef[z], basis[z * 961 + idx], ph);
        int dh = h - 15, dw = w - 15;
        bool m = (dh * dh + dw * dw) <= 225;
        float sv, cv;
        sincosf(ph, &sv, &cv);
        pupR[idx] = m ? cv : 0.0f;
        pupI[idx] = m ? sv : 0.0f;
    }
    __syncthreads();

    for (int idx = tid; idx < 961; idx += 256) {
        int h = idx / 31, k = idx % 31;
        float ar = 0.0f, ai = 0.0f;
        for (int w = 0; w < 31; ++w) {
            int tt = (k * w) % 31;
            float cr = rootR[tt], ci = rootI[tt];
            float pr = pupR[h * 31 + w], pi = pupI[h * 31 + w];
            ar += pr * cr - pi * ci;
            ai += pr * ci + pi * cr;
        }
        tR[idx] = ar; tI[idx] = ai;
    }
    __syncthreads();

    float lsum = 0.0f;
    for (int idx = tid; idx < 961; idx += 256) {
        int u = idx / 31, k = idx % 31;
        float gr = 0.0f, gi = 0.0f;
        for (int h = 0; h < 31; ++h) {
            int tt = (u * h) % 31;
            float cr = rootR[tt], ci = rootI[tt];
            float ar = tR[h * 31 + k], ai = tI[h * 31 + k];
            gr += ar * cr - ai * ci;
            gi += ar * ci + ai * cr;
        }
        float p = gr * gr + gi * gi;
        pupR[idx] = p;
        lsum += p;
    }
    red[tid] = lsum;
    __syncthreads();
    for (int off = 128; off > 0; off >>= 1) {
        if (tid < off) red[tid] += red[tid + off];
        __syncthreads();
    }
    float inv = 1.0f / (red[0] + 1e-12f);
    // kf[j,i] = psf_un[(15-j)%31, (15-i)%31] * inv  -> stash in tI (free now)
    for (int idx = tid; idx < 961; idx += 256) {
        int j = idx / 31, i = idx % 31;
        int u = (15 - j + 31) % 31, v = (15 - i + 31) % 31;
        tI[idx] = pupR[u * 31 + v] * inv;
    }
    __syncthreads();

    unsigned int* bf = bfrags + (size_t)n * BPOS_U32_;
    for (int w2 = tid; w2 < BPOS_U32_; w2 += 256) {
        int jc = w2 >> 8;            // 256 uints per fragment; jc = s*3 + c
        int s = jc / 3, c = jc % 3;
        int rem = w2 & 255;
        int l = rem >> 2, ew = rem & 3;
        int nn = l & 15, kg = l >> 4;
        unsigned int pack = 0;
        #pragma unroll
        for (int q = 0; q < 2; ++q) {
            int e = ew * 2 + q;
            int kk = kg * 8 + e;
            int jrow = 2 * s + (kk >> 4);
            int tap = 16 * c + (kk & 15) - nn;
            float v = (jrow <= 30 && tap >= 0 && tap <= 30) ? tI[jrow * 31 + tap] : 0.0f;
            pack |= (unsigned int)bf16_rne(v) << (16 * q);
        }
        bf[w2] = pack;
    }
}

// ---------------------------------------------------------------------------
// Kernel 2 (v7): depthwise 31x31 conv as row-pair banded bf16 MFMA GEMM.
// One block per (patch, channel): 128x128 out, 1024 threads = 16 waves
// (8 row-strips x 2 col-halves of 64). Per step s (2 kernel rows):
// 3 global B-fragment loads + 6 ds_read_b128 A-segments + 12 MFMA, acc[4].
// 2 blocks/CU (LDS 54KB) x 16 waves = 32 waves/CU (HW max).
// MODE 0 writes ypatch as bf16.
// ---------------------------------------------------------------------------
template<int MODE>
__global__ __launch_bounds__(1024, 8) void conv_mfma_kernel(
    const float* __restrict__ x, const unsigned int* __restrict__ bfrags,
    void* __restrict__ dst)
{
    __shared__ unsigned short sIn[TROWS_ * LSTRIDE_];   // 160*168*2 = 53760 B
    __shared__ float sH[128];

    int t = blockIdx.x;
    int cc = t % 3;
    int bn = t / 3;
    int b = bn / NPOS_, n = bn % NPOS_;
    int nh = n / 7, nw = n % 7;
    int r0 = nh * S_, c0 = nw * S_;
    int tid = threadIdx.x;

    if (tid < 128) sH[tid] = hann128(tid);

    // stage patch tile (zero-padded) as bf16: rows 0..159, cols 0..159 used
    // tile[r,c] = x[r0 + r-15, c0 + c-15] if 15 <= r,c < 143 else 0
    const float* xb = x + ((size_t)(b * C_ + cc) * HW_ + r0) * HW_ + c0;
    for (int i = tid; i < TROWS_ * 40; i += 1024) {
        int r = i / 40, c4 = (i % 40) * 4;
        bool rv = (r >= 15 && r < 143);
        unsigned int pk[2] = {0, 0};
        #pragma unroll
        for (int q = 0; q < 4; ++q) {
            int c = c4 + q;
            float v = 0.0f;
            if (rv && c >= 15 && c < 143) v = xb[(r - 15) * HW_ + (c - 15)];
            pk[q >> 1] |= (unsigned int)bf16_rne(v) << (16 * (q & 1));
        }
        *(uint2*)&sIn[r * LSTRIDE_ + c4] = make_uint2(pk[0], pk[1]);
    }
    __syncthreads();

    int lane = tid & 63, wv = tid >> 6;
    int m0 = (wv & 7) * 16;        // row strip
    int ch = (wv >> 3) * 64;       // col half
    int lrow = lane & 15, lkg = lane >> 4;

    f32x4 acc[4];
    #pragma unroll
    for (int q = 0; q < 4; ++q) acc[q] = (f32x4){0.f, 0.f, 0.f, 0.f};

    // A byte offset: row (m0+lrow + 2s + (lkg>>1)) * 336 + ch*2 + seg*32 + (lkg&1)*16
    int abase = (m0 + lrow + (lkg >> 1)) * (LSTRIDE_ * 2) + ch * 2 + (lkg & 1) * 16;
    const bf16x8* bpos = (const bf16x8*)(bfrags + (size_t)n * BPOS_U32_) + lane;

    #pragma unroll 1
    for (int s = 0; s < NSTEP_; ++s) {
        const bf16x8* bp = bpos + s * 192;
        bf16x8 B0 = bp[0], B1 = bp[64], B2 = bp[128];
        const char* ap = (const char*)sIn + abase;
        bf16x8 A[6];
        #pragma unroll
        for (int p = 0; p < 6; ++p) A[p] = *(const bf16x8*)(ap + p * 32);
        #pragma unroll
        for (int q = 0; q < 4; ++q) {
            acc[q] = __builtin_amdgcn_mfma_f32_16x16x32_bf16(A[q],     B0, acc[q], 0, 0, 0);
            acc[q] = __builtin_amdgcn_mfma_f32_16x16x32_bf16(A[q + 1], B1, acc[q], 0, 0, 0);
            acc[q] = __builtin_amdgcn_mfma_f32_16x16x32_bf16(A[q + 2], B2, acc[q], 0, 0, 0);
        }
        abase += 2 * (LSTRIDE_ * 2);
    }

    // epilogue: C/D layout col = lane&15, row = lkg*4 + r (m89-verified)
    float hy[4];
    #pragma unroll
    for (int r = 0; r < 4; ++r) hy[r] = sH[m0 + lkg * 4 + r];

    #pragma unroll
    for (int q = 0; q < 4; ++q) {
        int xloc = ch + 16 * q + lrow;
        float hxv = sH[xloc];
        #pragma unroll
        for (int r = 0; r < 4; ++r) {
            int yloc = m0 + lkg * 4 + r;
            float val = acc[q][r] * hy[r] * hxv;
            if (MODE == 0) {
                unsigned short* yp = (unsigned short*)dst + (((size_t)bn * C_ + cc) << 14);
                yp[yloc * P_ + xloc] = bf16_rne(val);
            } else {
                float* ob = (float*)dst;
                atomicAdd(ob + ((size_t)(b * C_ + cc) * HW_ + r0 + yloc) * HW_ + c0 + xloc, val);
            }
        }
    }
}

// ---------------------------------------------------------------------------
// Kernel 3a: gather overlap-add (x4 vectorized, bf16 patches), analytic divide
// ---------------------------------------------------------------------------
__global__ __launch_bounds__(256) void gather_kernel(
    const unsigned short* __restrict__ ypatch, float* __restrict__ out)
{
    __shared__ float sH[128];
    int tid = threadIdx.x;
    if (tid < 128) sH[tid] = hann128(tid);
    __syncthreads();

    int gid = blockIdx.x * 256 + tid;
    int base = gid * 4;
    if (base >= B_ * C_ * HW_ * HW_) return;
    int X = base & 511;
    int Y = (base >> 9) & 511;
    int bc = base >> 18;
    int c = bc % 3, b = bc / 3;
    int nhA = Y >> 6, pyA = Y & 63;
    int nwA = X >> 6, pxA = X & 63;       // multiple of 4
    bool vA = nhA <= 6, vB = nhA >= 1;
    bool uA = nwA <= 6, uB = nwA >= 1;
    float wy = (vA ? sH[pyA] : 0.0f) + (vB ? sH[pyA + 64] : 0.0f);

    float4 acc = {0.f, 0.f, 0.f, 0.f};
    #pragma unroll
    for (int sy = 0; sy < 2; ++sy) {
        bool okY = sy == 0 ? vA : vB;
        int nh = sy == 0 ? nhA : nhA - 1;
        int py = sy == 0 ? pyA : pyA + 64;
        #pragma unroll
        for (int sx = 0; sx < 2; ++sx) {
            bool okX = sx == 0 ? uA : uB;
            int nw = sx == 0 ? nwA : nwA - 1;
            int px = sx == 0 ? pxA : pxA + 64;
            if (okY && okX) {
                size_t off = ((((size_t)b * NPOS_ + nh * 7 + nw) * C_ + c) << 14) + (py << 7) + px;
                uint2 v = *(const uint2*)&ypatch[off];
                acc.x += bf16_to_f(v.x & 0xffffu);
                acc.y += bf16_to_f(v.x >> 16);
                acc.z += bf16_to_f(v.y & 0xffffu);
                acc.w += bf16_to_f(v.y >> 16);
            }
        }
    }
    float4 o;
    float wx0 = (uA ? sH[pxA + 0] : 0.0f) + (uB ? sH[pxA + 64] : 0.0f);
    float wx1 = (uA ? sH[pxA + 1] : 0.0f) + (uB ? sH[pxA + 65] : 0.0f);
    float wx2 = (uA ? sH[pxA + 2] : 0.0f) + (uB ? sH[pxA + 66] : 0.0f);
    float wx3 = (uA ? sH[pxA + 3] : 0.0f) + (uB ? sH[pxA + 67] : 0.0f);
    o.x = acc.x / (wy * wx0 + 1e-8f);
    o.y = acc.y / (wy * wx1 + 1e-8f);
    o.z = acc.z / (wy * wx2 + 1e-8f);
    o.w = acc.w / (wy * wx3 + 1e-8f);
    *(float4*)&out[base] = o;
}

// ---------------------------------------------------------------------------
// Kernel 3b: in-place divide (atomic fallback path)
// ---------------------------------------------------------------------------
__global__ __launch_bounds__(256) void divide_kernel(float* __restrict__ out)
{
    int idx = blockIdx.x * 256 + threadIdx.x;
    if (idx >= B_ * C_ * HW_ * HW_) return;
    int X = idx & 511;
    int Y = (idx >> 9) & 511;
    int nhA = Y >> 6, pyA = Y & 63;
    int nwA = X >> 6, pxA = X & 63;
    float wy = (nhA <= 6 ? hann128(pyA) : 0.0f) + (nhA >= 1 ? hann128(pyA + 64) : 0.0f);
    float wx = (nwA <= 6 ? hann128(pxA) : 0.0f) + (nwA >= 1 ? hann128(pxA + 64) : 0.0f);
    out[idx] = out[idx] / (wy * wx + 1e-8f);
}

extern "C" void kernel_launch(void* const* d_in, const int* in_sizes, int n_in,
                              void* d_out, int out_size, void* d_ws, size_t ws_size,
                              hipStream_t stream)
{
    const float* x    = (const float*)d_in[0];
    const float* w1   = (const float*)d_in[1];
    const float* b1   = (const float*)d_in[2];
    const float* w2   = (const float*)d_in[3];
    const float* b2   = (const float*)d_in[4];
    const float* w3   = (const float*)d_in[5];
    const float* b3   = (const float*)d_in[6];
    const float* basis = (const float*)d_in[7];
    float* out = (float*)d_out;

    unsigned int* bfrags = (unsigned int*)d_ws;
    size_t bfBytes = (size_t)NPOS_ * BPOS_U32_ * sizeof(unsigned int);            // ~2.41 MB
    size_t need = bfBytes + (size_t)BN_ * C_ * P_ * P_ * sizeof(unsigned short);  // + 38.5 MB

    psf_kernel<<<NPOS_, 256, 0, stream>>>(w1, b1, w2, b2, w3, b3, basis, bfrags);

    int nPix = B_ * C_ * HW_ * HW_;
    if (ws_size >= need) {
        unsigned short* ypatch = (unsigned short*)((char*)d_ws + bfBytes);
        conv_mfma_kernel<0><<<BN_ * C_, 1024, 0, stream>>>(x, bfrags, ypatch);
        gather_kernel<<<(nPix / 4 + 255) / 256, 256, 0, stream>>>(ypatch, out);
    } else {
        hipMemsetAsync(d_out, 0, (size_t)out_size * sizeof(float), stream);
        conv_mfma_kernel<1><<<BN_ * C_, 1024, 0, stream>>>(x, bfrags, out);
        divide_kernel<<<(nPix + 255) / 256, 256, 0, stream>>>(out);
    }
}

// Round 8
// 87.803 us; speedup vs baseline: 1.1592x; 1.1592x over previous
//
#include <hip/hip_runtime.h>
#include <math.h>

#define B_ 8
#define C_ 3
#define HW_ 512
#define P_ 128
#define S_ 64
#define K_ 31
#define NZ_ 15
#define HID_ 64
#define NPOS_ 49   // 7x7 patch positions
#define BN_ (B_*NPOS_)

#define LSTRIDE_ 168   // bf16 elems/row; 336 B = 21 x 16B blocks; 21 mod 8 = 5 (odd) -> conflict-free
#define TROWS_ 160     // 128 + 30 halo + 2 spare (rows 158,159 zero)
#define FRAG_U32_ 256  // one B fragment = 64 lanes x 16 B = 256 uints
#define NSTEP_ 16      // 16 row-pair steps cover j = 0..31 (row 31 masked to zero)
#define BPOS_U32_ (NSTEP_ * 3 * FRAG_U32_)  // 12288 uints per patch position

typedef __attribute__((ext_vector_type(8))) short bf16x8;
typedef __attribute__((ext_vector_type(4))) float f32x4;

__device__ __forceinline__ float hann128(int p) {
    return 0.5f - 0.5f * cosf(6.283185307179586f * (float)p / 128.0f);
}

__device__ __forceinline__ unsigned short bf16_rne(float f) {
    union { float f; unsigned int u; } v; v.f = f;
    unsigned int r = v.u + 0x7fffu + ((v.u >> 16) & 1u);
    return (unsigned short)(r >> 16);
}

__device__ __forceinline__ float bf16_to_f(unsigned int bits16) {
    union { unsigned int u; float f; } v; v.u = bits16 << 16;
    return v.f;
}

// ---------------------------------------------------------------------------
// Kernel 1 (v8: 1024 threads): MLP + pupil + 31x31 DFT -> normalized flipped
// kernel -> row-pair B-fragment precompute. One block per position (49).
// Fragment (s, c): logical k in [0,32): jrow = 2s + (k>=16),
//   B_c[k][n] = kf[jrow, 16c + (k&15) - n] if valid else 0.
// Lane labeling (matches conv A reads, empirically validated r4-r7):
//   lane l: n = l&15, k = (l>>4)*8 + e, e = 0..7.
// ---------------------------------------------------------------------------
__global__ __launch_bounds__(1024) void psf_kernel(
    const float* __restrict__ w1, const float* __restrict__ b1,
    const float* __restrict__ w2, const float* __restrict__ b2,
    const float* __restrict__ w3, const float* __restrict__ b3,
    const float* __restrict__ basis, unsigned int* __restrict__ bfrags)
{
    __shared__ float h1[HID_], h2[HID_], coef[NZ_];
    __shared__ float pupR[961], pupI[961], tR[961], tI[961];
    __shared__ float rootR[31], rootI[31];
    __shared__ float red[16];
    int n = blockIdx.x;
    int nh = n / 7, nw = n % 7;
    int tid = threadIdx.x;
    float cy = (float)(nh * S_ + P_ / 2) * (2.0f / (float)HW_) - 1.0f;
    float cx = (float)(nw * S_ + P_ / 2) * (2.0f / (float)HW_) - 1.0f;

    if (tid < HID_) h1[tid] = fmaxf(0.0f, cy * w1[tid] + cx * w1[HID_ + tid] + b1[tid]);
    if (tid < 31) {
        float ang = -6.283185307179586f * (float)tid / 31.0f;
        rootR[tid] = cosf(ang);
        rootI[tid] = sinf(ang);
    }
    __syncthreads();
    if (tid < HID_) {
        float s = b2[tid];
        for (int k = 0; k < HID_; ++k) s = fmaf(h1[k], w2[k * HID_ + tid], s);
        h2[tid] = fmaxf(0.0f, s);
    }
    __syncthreads();
    if (tid < NZ_) {
        float s = b3[tid];
        for (int k = 0; k < HID_; ++k) s = fmaf(h2[k], w3[k * NZ_ + tid], s);
        coef[tid] = s;
    }
    __syncthreads();

    for (int idx = tid; idx < 961; idx += 1024) {
        int h = idx / 31, w = idx % 31;
        float ph = 0.0f;
        for (int z = 0; z < NZ_; ++z) ph = fmaf(coef[z], basis[z * 961 + idx], ph);
        int dh = h - 15, dw = w - 15;
        bool m = (dh * dh + dw * dw) <= 225;
        float sv, cv;
        sincosf(ph, &sv, &cv);
        pupR[idx] = m ? cv : 0.0f;
        pupI[idx] = m ? sv : 0.0f;
    }
    __syncthreads();

    for (int idx = tid; idx < 961; idx += 1024) {
        int h = idx / 31, k = idx % 31;
        float ar = 0.0f, ai = 0.0f;
        for (int w = 0; w < 31; ++w) {
            int tt = (k * w) % 31;
            float cr = rootR[tt], ci = rootI[tt];
            float pr = pupR[h * 31 + w], pi = pupI[h * 31 + w];
            ar += pr * cr - pi * ci;
            ai += pr * ci + pi * cr;
        }
        tR[idx] = ar; tI[idx] = ai;
    }
    __syncthreads();

    float lsum = 0.0f;
    for (int idx = tid; idx < 961; idx += 1024) {
        int u = idx / 31, k = idx % 31;
        float gr = 0.0f, gi = 0.0f;
        for (int h = 0; h < 31; ++h) {
            int tt = (u * h) % 31;
            float cr = rootR[tt], ci = rootI[tt];
            float ar = tR[h * 31 + k], ai = tI[h * 31 + k];
            gr += ar * cr - ai * ci;
            gi += ar * ci + ai * cr;
        }
        float p = gr * gr + gi * gi;
        pupR[idx] = p;
        lsum += p;
    }
    // wave-level reduce then cross-wave combine
    float v = lsum;
    #pragma unroll
    for (int off = 32; off >= 1; off >>= 1) v += __shfl_xor(v, off, 64);
    if ((tid & 63) == 0) red[tid >> 6] = v;
    __syncthreads();
    if (tid == 0) {
        float s = 0.0f;
        #pragma unroll
        for (int i = 0; i < 16; ++i) s += red[i];
        red[0] = 1.0f / (s + 1e-12f);
    }
    __syncthreads();
    float inv = red[0];
    // kf[j,i] = psf_un[(15-j)%31, (15-i)%31] * inv  -> stash in tI (free now)
    for (int idx = tid; idx < 961; idx += 1024) {
        int j = idx / 31, i = idx % 31;
        int u = (15 - j + 31) % 31, vv = (15 - i + 31) % 31;
        tI[idx] = pupR[u * 31 + vv] * inv;
    }
    __syncthreads();

    unsigned int* bf = bfrags + (size_t)n * BPOS_U32_;
    for (int w2 = tid; w2 < BPOS_U32_; w2 += 1024) {
        int jc = w2 >> 8;            // 256 uints per fragment; jc = s*3 + c
        int s = jc / 3, c = jc % 3;
        int rem = w2 & 255;
        int l = rem >> 2, ew = rem & 3;
        int nn = l & 15, kg = l >> 4;
        unsigned int pack = 0;
        #pragma unroll
        for (int q = 0; q < 2; ++q) {
            int e = ew * 2 + q;
            int kk = kg * 8 + e;
            int jrow = 2 * s + (kk >> 4);
            int tap = 16 * c + (kk & 15) - nn;
            float vx = (jrow <= 30 && tap >= 0 && tap <= 30) ? tI[jrow * 31 + tap] : 0.0f;
            pack |= (unsigned int)bf16_rne(vx) << (16 * q);
        }
        bf[w2] = pack;
    }
}

// ---------------------------------------------------------------------------
// Kernel 2 (v8): row-pair banded bf16 MFMA GEMM with B double-buffering.
// One block per (patch, channel): 128x128 out, 1024 threads = 16 waves
// (8 row-strips x 2 col-halves of 64). Per step s: issue 3 global B(s+1)
// loads FIRST (latency hidden under MFMA(s)), then 6 ds_read_b128 A(s),
// then 12 MFMA with the previously-fetched B(s). 2 blocks/CU, 32 waves/CU.
// ---------------------------------------------------------------------------
template<int MODE>
__global__ __launch_bounds__(1024, 8) void conv_mfma_kernel(
    const float* __restrict__ x, const unsigned int* __restrict__ bfrags,
    void* __restrict__ dst)
{
    __shared__ unsigned short sIn[TROWS_ * LSTRIDE_];   // 160*168*2 = 53760 B
    __shared__ float sH[128];

    int t = blockIdx.x;
    int cc = t % 3;
    int bn = t / 3;
    int b = bn / NPOS_, n = bn % NPOS_;
    int nh = n / 7, nw = n % 7;
    int r0 = nh * S_, c0 = nw * S_;
    int tid = threadIdx.x;

    if (tid < 128) sH[tid] = hann128(tid);

    // stage patch tile (zero-padded) as bf16: rows 0..159, cols 0..159 used
    // tile[r,c] = x[r0 + r-15, c0 + c-15] if 15 <= r,c < 143 else 0
    const float* xb = x + ((size_t)(b * C_ + cc) * HW_ + r0) * HW_ + c0;
    for (int i = tid; i < TROWS_ * 40; i += 1024) {
        int r = i / 40, c4 = (i % 40) * 4;
        bool rv = (r >= 15 && r < 143);
        unsigned int pk[2] = {0, 0};
        #pragma unroll
        for (int q = 0; q < 4; ++q) {
            int c = c4 + q;
            float v = 0.0f;
            if (rv && c >= 15 && c < 143) v = xb[(r - 15) * HW_ + (c - 15)];
            pk[q >> 1] |= (unsigned int)bf16_rne(v) << (16 * (q & 1));
        }
        *(uint2*)&sIn[r * LSTRIDE_ + c4] = make_uint2(pk[0], pk[1]);
    }
    __syncthreads();

    int lane = tid & 63, wv = tid >> 6;
    int m0 = (wv & 7) * 16;        // row strip
    int ch = (wv >> 3) * 64;       // col half
    int lrow = lane & 15, lkg = lane >> 4;

    f32x4 acc[4];
    #pragma unroll
    for (int q = 0; q < 4; ++q) acc[q] = (f32x4){0.f, 0.f, 0.f, 0.f};

    // A byte offset: row (m0+lrow + 2s + (lkg>>1)) * 336 + ch*2 + seg*32 + (lkg&1)*16
    int abase = (m0 + lrow + (lkg >> 1)) * (LSTRIDE_ * 2) + ch * 2 + (lkg & 1) * 16;
    const bf16x8* bpos = (const bf16x8*)(bfrags + (size_t)n * BPOS_U32_) + lane;

    bf16x8 Bc0 = bpos[0], Bc1 = bpos[64], Bc2 = bpos[128];

    #pragma unroll 2
    for (int s = 0; s < NSTEP_; ++s) {
        bf16x8 Bn0, Bn1, Bn2;
        if (s + 1 < NSTEP_) {
            const bf16x8* bnp = bpos + (s + 1) * 192;
            Bn0 = bnp[0]; Bn1 = bnp[64]; Bn2 = bnp[128];
        } else {
            Bn0 = Bc0; Bn1 = Bc1; Bn2 = Bc2;
        }
        const char* ap = (const char*)sIn + abase;
        bf16x8 A[6];
        #pragma unroll
        for (int p = 0; p < 6; ++p) A[p] = *(const bf16x8*)(ap + p * 32);
        #pragma unroll
        for (int q = 0; q < 4; ++q) {
            acc[q] = __builtin_amdgcn_mfma_f32_16x16x32_bf16(A[q],     Bc0, acc[q], 0, 0, 0);
            acc[q] = __builtin_amdgcn_mfma_f32_16x16x32_bf16(A[q + 1], Bc1, acc[q], 0, 0, 0);
            acc[q] = __builtin_amdgcn_mfma_f32_16x16x32_bf16(A[q + 2], Bc2, acc[q], 0, 0, 0);
        }
        Bc0 = Bn0; Bc1 = Bn1; Bc2 = Bn2;
        abase += 2 * (LSTRIDE_ * 2);
    }

    // epilogue: C/D layout col = lane&15, row = lkg*4 + r (m89-verified)
    float hy[4];
    #pragma unroll
    for (int r = 0; r < 4; ++r) hy[r] = sH[m0 + lkg * 4 + r];

    #pragma unroll
    for (int q = 0; q < 4; ++q) {
        int xloc = ch + 16 * q + lrow;
        float hxv = sH[xloc];
        #pragma unroll
        for (int r = 0; r < 4; ++r) {
            int yloc = m0 + lkg * 4 + r;
            float val = acc[q][r] * hy[r] * hxv;
            if (MODE == 0) {
                unsigned short* yp = (unsigned short*)dst + (((size_t)bn * C_ + cc) << 14);
                yp[yloc * P_ + xloc] = bf16_rne(val);
            } else {
                float* ob = (float*)dst;
                atomicAdd(ob + ((size_t)(b * C_ + cc) * HW_ + r0 + yloc) * HW_ + c0 + xloc, val);
            }
        }
    }
}

// ---------------------------------------------------------------------------
// Kernel 3a: gather overlap-add (x4 vectorized, bf16 patches), analytic divide
// ---------------------------------------------------------------------------
__global__ __launch_bounds__(256) void gather_kernel(
    const unsigned short* __restrict__ ypatch, float* __restrict__ out)
{
    __shared__ float sH[128];
    int tid = threadIdx.x;
    if (tid < 128) sH[tid] = hann128(tid);
    __syncthreads();

    int gid = blockIdx.x * 256 + tid;
    int base = gid * 4;
    if (base >= B_ * C_ * HW_ * HW_) return;
    int X = base & 511;
    int Y = (base >> 9) & 511;
    int bc = base >> 18;
    int c = bc % 3, b = bc / 3;
    int nhA = Y >> 6, pyA = Y & 63;
    int nwA = X >> 6, pxA = X & 63;       // multiple of 4
    bool vA = nhA <= 6, vB = nhA >= 1;
    bool uA = nwA <= 6, uB = nwA >= 1;
    float wy = (vA ? sH[pyA] : 0.0f) + (vB ? sH[pyA + 64] : 0.0f);

    float4 acc = {0.f, 0.f, 0.f, 0.f};
    #pragma unroll
    for (int sy = 0; sy < 2; ++sy) {
        bool okY = sy == 0 ? vA : vB;
        int nh = sy == 0 ? nhA : nhA - 1;
        int py = sy == 0 ? pyA : pyA + 64;
        #pragma unroll
        for (int sx = 0; sx < 2; ++sx) {
            bool okX = sx == 0 ? uA : uB;
            int nw = sx == 0 ? nwA : nwA - 1;
            int px = sx == 0 ? pxA : pxA + 64;
            if (okY && okX) {
                size_t off = ((((size_t)b * NPOS_ + nh * 7 + nw) * C_ + c) << 14) + (py << 7) + px;
                uint2 v = *(const uint2*)&ypatch[off];
                acc.x += bf16_to_f(v.x & 0xffffu);
                acc.y += bf16_to_f(v.x >> 16);
                acc.z += bf16_to_f(v.y & 0xffffu);
                acc.w += bf16_to_f(v.y >> 16);
            }
        }
    }
    float4 o;
    float wx0 = (uA ? sH[pxA + 0] : 0.0f) + (uB ? sH[pxA + 64] : 0.0f);
    float wx1 = (uA ? sH[pxA + 1] : 0.0f) + (uB ? sH[pxA + 65] : 0.0f);
    float wx2 = (uA ? sH[pxA + 2] : 0.0f) + (uB ? sH[pxA + 66] : 0.0f);
    float wx3 = (uA ? sH[pxA + 3] : 0.0f) + (uB ? sH[pxA + 67] : 0.0f);
    o.x = acc.x / (wy * wx0 + 1e-8f);
    o.y = acc.y / (wy * wx1 + 1e-8f);
    o.z = acc.z / (wy * wx2 + 1e-8f);
    o.w = acc.w / (wy * wx3 + 1e-8f);
    *(float4*)&out[base] = o;
}

// ---------------------------------------------------------------------------
// Kernel 3b: in-place divide (atomic fallback path)
// ---------------------------------------------------------------------------
__global__ __launch_bounds__(256) void divide_kernel(float* __restrict__ out)
{
    int idx = blockIdx.x * 256 + threadIdx.x;
    if (idx >= B_ * C_ * HW_ * HW_) return;
    int X = idx & 511;
    int Y = (idx >> 9) & 511;
    int nhA = Y >> 6, pyA = Y & 63;
    int nwA = X >> 6, pxA = X & 63;
    float wy = (nhA <= 6 ? hann128(pyA) : 0.0f) + (nhA >= 1 ? hann128(pyA + 64) : 0.0f);
    float wx = (nwA <= 6 ? hann128(pxA) : 0.0f) + (nwA >= 1 ? hann128(pxA + 64) : 0.0f);
    out[idx] = out[idx] / (wy * wx + 1e-8f);
}

extern "C" void kernel_launch(void* const* d_in, const int* in_sizes, int n_in,
                              void* d_out, int out_size, void* d_ws, size_t ws_size,
                              hipStream_t stream)
{
    const float* x    = (const float*)d_in[0];
    const float* w1   = (const float*)d_in[1];
    const float* b1   = (const float*)d_in[2];
    const float* w2   = (const float*)d_in[3];
    const float* b2   = (const float*)d_in[4];
    const float* w3   = (const float*)d_in[5];
    const float* b3   = (const float*)d_in[6];
    const float* basis = (const float*)d_in[7];
    float* out = (float*)d_out;

    unsigned int* bfrags = (unsigned int*)d_ws;
    size_t bfBytes = (size_t)NPOS_ * BPOS_U32_ * sizeof(unsigned int);            // ~2.41 MB
    size_t need = bfBytes + (size_t)BN_ * C_ * P_ * P_ * sizeof(unsigned short);  // + 38.5 MB

    psf_kernel<<<NPOS_, 1024, 0, stream>>>(w1, b1, w2, b2, w3, b3, basis, bfrags);

    int nPix = B_ * C_ * HW_ * HW_;
    if (ws_size >= need) {
        unsigned short* ypatch = (unsigned short*)((char*)d_ws + bfBytes);
        conv_mfma_kernel<0><<<BN_ * C_, 1024, 0, stream>>>(x, bfrags, ypatch);
        gather_kernel<<<(nPix / 4 + 255) / 256, 256, 0, stream>>>(ypatch, out);
    } else {
        hipMemsetAsync(d_out, 0, (size_t)out_size * sizeof(float), stream);
        conv_mfma_kernel<1><<<BN_ * C_, 1024, 0, stream>>>(x, bfrags, out);
        divide_kernel<<<(nPix + 255) / 256, 256, 0, stream>>>(out);
    }
}

// Round 9
// 86.120 us; speedup vs baseline: 1.1818x; 1.0195x over previous
//
#include <hip/hip_runtime.h>
#include <math.h>

#define B_ 8
#define C_ 3
#define HW_ 512
#define P_ 128
#define S_ 64
#define K_ 31
#define NZ_ 15
#define HID_ 64
#define NPOS_ 49   // 7x7 patch positions
#define BN_ (B_*NPOS_)

#define LSTRIDE_ 168   // bf16 elems/row; 336 B = 21 x 16B blocks (odd -> conflict-free b128)
#define TROWS_ 96      // 64-row half + 31 halo + 1 spare
#define FRAG_U32_ 256  // one B fragment = 64 lanes x 16 B = 256 uints
#define NSTEP_ 16      // 16 row-pair steps cover kernel rows via jrow = 2s + (k>=16), jrow=0 masked
#define BPOS_U32_ (NSTEP_ * 3 * FRAG_U32_)  // 12288 uints per patch position

typedef __attribute__((ext_vector_type(8))) short bf16x8;
typedef __attribute__((ext_vector_type(4))) float f32x4;

__device__ __forceinline__ float hann128(int p) {
    return 0.5f - 0.5f * cosf(6.283185307179586f * (float)p / 128.0f);
}

__device__ __forceinline__ unsigned short bf16_rne(float f) {
    union { float f; unsigned int u; } v; v.f = f;
    unsigned int r = v.u + 0x7fffu + ((v.u >> 16) & 1u);
    return (unsigned short)(r >> 16);
}

__device__ __forceinline__ float bf16_to_f(unsigned int bits16) {
    union { unsigned int u; float f; } v; v.u = bits16 << 16;
    return v.f;
}

// ---------------------------------------------------------------------------
// Kernel 1: MLP + pupil + 31x31 DFT -> normalized flipped kernel -> row-pair
// B-fragment precompute (halo-16 convention). One block per position (49).
// Fragment (s, c), logical k in [0,32): jrow = 2s + (k>=16),
//   B_c[k][n] = kf[jrow-1, 16c + (k&15) - n - 1] if jrow,tap in 1..31 else 0.
// Lane labeling (matches conv A reads, empirically validated r4-r8):
//   lane l: n = l&15, k = (l>>4)*8 + e, e = 0..7.
// ---------------------------------------------------------------------------
__global__ __launch_bounds__(1024) void psf_kernel(
    const float* __restrict__ w1, const float* __restrict__ b1,
    const float* __restrict__ w2, const float* __restrict__ b2,
    const float* __restrict__ w3, const float* __restrict__ b3,
    const float* __restrict__ basis, unsigned int* __restrict__ bfrags)
{
    __shared__ float h1[HID_], h2[HID_], coef[NZ_];
    __shared__ float pupR[961], pupI[961], tR[961], tI[961];
    __shared__ float rootR[31], rootI[31];
    __shared__ float red[16];
    int n = blockIdx.x;
    int nh = n / 7, nw = n % 7;
    int tid = threadIdx.x;
    float cy = (float)(nh * S_ + P_ / 2) * (2.0f / (float)HW_) - 1.0f;
    float cx = (float)(nw * S_ + P_ / 2) * (2.0f / (float)HW_) - 1.0f;

    if (tid < HID_) h1[tid] = fmaxf(0.0f, cy * w1[tid] + cx * w1[HID_ + tid] + b1[tid]);
    if (tid < 31) {
        float ang = -6.283185307179586f * (float)tid / 31.0f;
        rootR[tid] = cosf(ang);
        rootI[tid] = sinf(ang);
    }
    __syncthreads();
    if (tid < HID_) {
        float s = b2[tid];
        for (int k = 0; k < HID_; ++k) s = fmaf(h1[k], w2[k * HID_ + tid], s);
        h2[tid] = fmaxf(0.0f, s);
    }
    __syncthreads();
    if (tid < NZ_) {
        float s = b3[tid];
        for (int k = 0; k < HID_; ++k) s = fmaf(h2[k], w3[k * NZ_ + tid], s);
        coef[tid] = s;
    }
    __syncthreads();

    for (int idx = tid; idx < 961; idx += 1024) {
        int h = idx / 31, w = idx % 31;
        float ph = 0.0f;
        for (int z = 0; z < NZ_; ++z) ph = fmaf(coef[z], basis[z * 961 + idx], ph);
        int dh = h - 15, dw = w - 15;
        bool m = (dh * dh + dw * dw) <= 225;
        float sv, cv;
        sincosf(ph, &sv, &cv);
        pupR[idx] = m ? cv : 0.0f;
        pupI[idx] = m ? sv : 0.0f;
    }
    __syncthreads();

    for (int idx = tid; idx < 961; idx += 1024) {
        int h = idx / 31, k = idx % 31;
        float ar = 0.0f, ai = 0.0f;
        for (int w = 0; w < 31; ++w) {
            int tt = (k * w) % 31;
            float cr = rootR[tt], ci = rootI[tt];
            float pr = pupR[h * 31 + w], pi = pupI[h * 31 + w];
            ar += pr * cr - pi * ci;
            ai += pr * ci + pi * cr;
        }
        tR[idx] = ar; tI[idx] = ai;
    }
    __syncthreads();

    float lsum = 0.0f;
    for (int idx = tid; idx < 961; idx += 1024) {
        int u = idx / 31, k = idx % 31;
        float gr = 0.0f, gi = 0.0f;
        for (int h = 0; h < 31; ++h) {
            int tt = (u * h) % 31;
            float cr = rootR[tt], ci = rootI[tt];
            float ar = tR[h * 31 + k], ai = tI[h * 31 + k];
            gr += ar * cr - ai * ci;
            gi += ar * ci + ai * cr;
        }
        float p = gr * gr + gi * gi;
        pupR[idx] = p;
        lsum += p;
    }
    float v = lsum;
    #pragma unroll
    for (int off = 32; off >= 1; off >>= 1) v += __shfl_xor(v, off, 64);
    if ((tid & 63) == 0) red[tid >> 6] = v;
    __syncthreads();
    if (tid == 0) {
        float s = 0.0f;
        #pragma unroll
        for (int i = 0; i < 16; ++i) s += red[i];
        red[0] = 1.0f / (s + 1e-12f);
    }
    __syncthreads();
    float inv = red[0];
    // kf[j,i] = psf_un[(15-j)%31, (15-i)%31] * inv  -> stash in tI (free now)
    for (int idx = tid; idx < 961; idx += 1024) {
        int j = idx / 31, i = idx % 31;
        int u = (15 - j + 31) % 31, vv = (15 - i + 31) % 31;
        tI[idx] = pupR[u * 31 + vv] * inv;
    }
    __syncthreads();

    unsigned int* bf = bfrags + (size_t)n * BPOS_U32_;
    for (int w2 = tid; w2 < BPOS_U32_; w2 += 1024) {
        int jc = w2 >> 8;            // 256 uints per fragment; jc = s*3 + c
        int s = jc / 3, c = jc % 3;
        int rem = w2 & 255;
        int l = rem >> 2, ew = rem & 3;
        int nn = l & 15, kg = l >> 4;
        unsigned int pack = 0;
        #pragma unroll
        for (int q = 0; q < 2; ++q) {
            int e = ew * 2 + q;
            int kk = kg * 8 + e;
            int jrow = 2 * s + (kk >> 4);          // halo-16: kernel row = jrow-1
            int tap = 16 * c + (kk & 15) - nn;     // halo-16: kernel col = tap-1
            float vx = (jrow >= 1 && jrow <= 31 && tap >= 1 && tap <= 31)
                       ? tI[(jrow - 1) * 31 + (tap - 1)] : 0.0f;
            pack |= (unsigned int)bf16_rne(vx) << (16 * q);
        }
        bf[w2] = pack;
    }
}

// ---------------------------------------------------------------------------
// Kernel 2 (v9): row-pair banded bf16 MFMA GEMM, 2-deep A+B register prefetch.
// One block per (patch, channel, row-half): 64x128 out, 512 threads = 8 waves
// (4 row-strips x 2 col-halves). LDS tile 96x168 bf16 (halo-16: tile[r][c]
// <-> patch[half*64 + r - 16][c - 16]), 32 KB -> 2 blocks/CU co-resident so
// staging overlaps the other block's compute. Per step: prefetch A(s+1)
// (6 ds_read_b128) + B(s+1) (3 global) BEFORE the 12 MFMAs of step s.
// ---------------------------------------------------------------------------
template<int MODE>
__global__ __launch_bounds__(512, 4) void conv_mfma_kernel(
    const float* __restrict__ x, const unsigned int* __restrict__ bfrags,
    void* __restrict__ dst)
{
    __shared__ unsigned short sIn[TROWS_ * LSTRIDE_];   // 96*168*2 = 32256 B
    __shared__ float sH[128];

    int t = blockIdx.x;
    int half = t & 1;
    int cc = (t >> 1) % 3;
    int bn = t / 6;
    int b = bn / NPOS_, n = bn % NPOS_;
    int nh = n / 7, nw = n % 7;
    int r0 = nh * S_, c0 = nw * S_;
    int tid = threadIdx.x;

    if (tid < 128) sH[tid] = hann128(tid);

    // zero-fill tile (halo + invalid rows stay zero)
    for (int i = tid; i < TROWS_ * LSTRIDE_ * 2 / 16; i += 512)
        ((uint4*)sIn)[i] = make_uint4(0u, 0u, 0u, 0u);
    __syncthreads();

    // stage interior: tile row r <-> patch row half*64 + r - 16; cols 16..143
    const float* xb = x + ((size_t)(b * C_ + cc) * HW_ + r0) * HW_ + c0;
    int rpbase = half * 64 - 16;
    for (int i = tid; i < TROWS_ * 32; i += 512) {
        int r = i >> 5, c4 = (i & 31) * 4;   // c4 = patch col 0,4,...,124
        int rp = rpbase + r;
        if (rp >= 0 && rp < P_) {
            float4 v = *(const float4*)&xb[rp * HW_ + c4];
            unsigned int lo = (unsigned int)bf16_rne(v.x) | ((unsigned int)bf16_rne(v.y) << 16);
            unsigned int hi = (unsigned int)bf16_rne(v.z) | ((unsigned int)bf16_rne(v.w) << 16);
            *(uint2*)&sIn[r * LSTRIDE_ + 16 + c4] = make_uint2(lo, hi);
        }
    }
    __syncthreads();

    int lane = tid & 63, wv = tid >> 6;
    int m0 = (wv & 3) * 16;        // row strip within the 64-row half
    int ch = (wv >> 2) * 64;       // col half
    int lrow = lane & 15, lkg = lane >> 4;

    f32x4 acc[4];
    #pragma unroll
    for (int q = 0; q < 4; ++q) acc[q] = (f32x4){0.f, 0.f, 0.f, 0.f};

    int abase = (m0 + lrow + (lkg >> 1)) * (LSTRIDE_ * 2) + ch * 2 + (lkg & 1) * 16;
    const bf16x8* bpos = (const bf16x8*)(bfrags + (size_t)n * BPOS_U32_) + lane;

    // prologue: load step 0
    bf16x8 Ac[6];
    {
        const char* ap = (const char*)sIn + abase;
        #pragma unroll
        for (int p = 0; p < 6; ++p) Ac[p] = *(const bf16x8*)(ap + p * 32);
    }
    bf16x8 Bc0 = bpos[0], Bc1 = bpos[64], Bc2 = bpos[128];

    #pragma unroll 3
    for (int s = 0; s < NSTEP_ - 1; ++s) {
        abase += 2 * (LSTRIDE_ * 2);
        // prefetch step s+1 (A from LDS, B from global) before MFMAs of step s
        bf16x8 An[6];
        const char* ap = (const char*)sIn + abase;
        #pragma unroll
        for (int p = 0; p < 6; ++p) An[p] = *(const bf16x8*)(ap + p * 32);
        const bf16x8* bnp = bpos + (s + 1) * 192;
        bf16x8 Bn0 = bnp[0], Bn1 = bnp[64], Bn2 = bnp[128];

        #pragma unroll
        for (int q = 0; q < 4; ++q) {
            acc[q] = __builtin_amdgcn_mfma_f32_16x16x32_bf16(Ac[q],     Bc0, acc[q], 0, 0, 0);
            acc[q] = __builtin_amdgcn_mfma_f32_16x16x32_bf16(Ac[q + 1], Bc1, acc[q], 0, 0, 0);
            acc[q] = __builtin_amdgcn_mfma_f32_16x16x32_bf16(Ac[q + 2], Bc2, acc[q], 0, 0, 0);
        }
        #pragma unroll
        for (int p = 0; p < 6; ++p) Ac[p] = An[p];
        Bc0 = Bn0; Bc1 = Bn1; Bc2 = Bn2;
    }
    // last step
    #pragma unroll
    for (int q = 0; q < 4; ++q) {
        acc[q] = __builtin_amdgcn_mfma_f32_16x16x32_bf16(Ac[q],     Bc0, acc[q], 0, 0, 0);
        acc[q] = __builtin_amdgcn_mfma_f32_16x16x32_bf16(Ac[q + 1], Bc1, acc[q], 0, 0, 0);
        acc[q] = __builtin_amdgcn_mfma_f32_16x16x32_bf16(Ac[q + 2], Bc2, acc[q], 0, 0, 0);
    }

    // epilogue: C/D layout col = lane&15, row = lkg*4 + r (m89-verified)
    int prow0 = half * 64 + m0 + lkg * 4;
    float hy[4];
    #pragma unroll
    for (int r = 0; r < 4; ++r) hy[r] = sH[prow0 + r];

    #pragma unroll
    for (int q = 0; q < 4; ++q) {
        int pcol = ch + 16 * q + lrow;
        float hxv = sH[pcol];
        #pragma unroll
        for (int r = 0; r < 4; ++r) {
            int prow = prow0 + r;
            float val = acc[q][r] * hy[r] * hxv;
            if (MODE == 0) {
                unsigned short* yp = (unsigned short*)dst + (((size_t)bn * C_ + cc) << 14);
                yp[prow * P_ + pcol] = bf16_rne(val);
            } else {
                float* ob = (float*)dst;
                atomicAdd(ob + ((size_t)(b * C_ + cc) * HW_ + r0 + prow) * HW_ + c0 + pcol, val);
            }
        }
    }
}

// ---------------------------------------------------------------------------
// Kernel 3a: gather overlap-add (x4 vectorized, bf16 patches), analytic divide
// ---------------------------------------------------------------------------
__global__ __launch_bounds__(256) void gather_kernel(
    const unsigned short* __restrict__ ypatch, float* __restrict__ out)
{
    __shared__ float sH[128];
    int tid = threadIdx.x;
    if (tid < 128) sH[tid] = hann128(tid);
    __syncthreads();

    int gid = blockIdx.x * 256 + tid;
    int base = gid * 4;
    if (base >= B_ * C_ * HW_ * HW_) return;
    int X = base & 511;
    int Y = (base >> 9) & 511;
    int bc = base >> 18;
    int c = bc % 3, b = bc / 3;
    int nhA = Y >> 6, pyA = Y & 63;
    int nwA = X >> 6, pxA = X & 63;       // multiple of 4
    bool vA = nhA <= 6, vB = nhA >= 1;
    bool uA = nwA <= 6, uB = nwA >= 1;
    float wy = (vA ? sH[pyA] : 0.0f) + (vB ? sH[pyA + 64] : 0.0f);

    float4 acc = {0.f, 0.f, 0.f, 0.f};
    #pragma unroll
    for (int sy = 0; sy < 2; ++sy) {
        bool okY = sy == 0 ? vA : vB;
        int nh = sy == 0 ? nhA : nhA - 1;
        int py = sy == 0 ? pyA : pyA + 64;
        #pragma unroll
        for (int sx = 0; sx < 2; ++sx) {
            bool okX = sx == 0 ? uA : uB;
            int nw = sx == 0 ? nwA : nwA - 1;
            int px = sx == 0 ? pxA : pxA + 64;
            if (okY && okX) {
                size_t off = ((((size_t)b * NPOS_ + nh * 7 + nw) * C_ + c) << 14) + (py << 7) + px;
                uint2 v = *(const uint2*)&ypatch[off];
                acc.x += bf16_to_f(v.x & 0xffffu);
                acc.y += bf16_to_f(v.x >> 16);
                acc.z += bf16_to_f(v.y & 0xffffu);
                acc.w += bf16_to_f(v.y >> 16);
            }
        }
    }
    float4 o;
    float wx0 = (uA ? sH[pxA + 0] : 0.0f) + (uB ? sH[pxA + 64] : 0.0f);
    float wx1 = (uA ? sH[pxA + 1] : 0.0f) + (uB ? sH[pxA + 65] : 0.0f);
    float wx2 = (uA ? sH[pxA + 2] : 0.0f) + (uB ? sH[pxA + 66] : 0.0f);
    float wx3 = (uA ? sH[pxA + 3] : 0.0f) + (uB ? sH[pxA + 67] : 0.0f);
    o.x = acc.x / (wy * wx0 + 1e-8f);
    o.y = acc.y / (wy * wx1 + 1e-8f);
    o.z = acc.z / (wy * wx2 + 1e-8f);
    o.w = acc.w / (wy * wx3 + 1e-8f);
    *(float4*)&out[base] = o;
}

// ---------------------------------------------------------------------------
// Kernel 3b: in-place divide (atomic fallback path)
// ---------------------------------------------------------------------------
__global__ __launch_bounds__(256) void divide_kernel(float* __restrict__ out)
{
    int idx = blockIdx.x * 256 + threadIdx.x;
    if (idx >= B_ * C_ * HW_ * HW_) return;
    int X = idx & 511;
    int Y = (idx >> 9) & 511;
    int nhA = Y >> 6, pyA = Y & 63;
    int nwA = X >> 6, pxA = X & 63;
    float wy = (nhA <= 6 ? hann128(pyA) : 0.0f) + (nhA >= 1 ? hann128(pyA + 64) : 0.0f);
    float wx = (nwA <= 6 ? hann128(pxA) : 0.0f) + (nwA >= 1 ? hann128(pxA + 64) : 0.0f);
    out[idx] = out[idx] / (wy * wx + 1e-8f);
}

extern "C" void kernel_launch(void* const* d_in, const int* in_sizes, int n_in,
                              void* d_out, int out_size, void* d_ws, size_t ws_size,
                              hipStream_t stream)
{
    const float* x    = (const float*)d_in[0];
    const float* w1   = (const float*)d_in[1];
    const float* b1   = (const float*)d_in[2];
    const float* w2   = (const float*)d_in[3];
    const float* b2   = (const float*)d_in[4];
    const float* w3   = (const float*)d_in[5];
    const float* b3   = (const float*)d_in[6];
    const float* basis = (const float*)d_in[7];
    float* out = (float*)d_out;

    unsigned int* bfrags = (unsigned int*)d_ws;
    size_t bfBytes = (size_t)NPOS_ * BPOS_U32_ * sizeof(unsigned int);            // ~2.41 MB
    size_t need = bfBytes + (size_t)BN_ * C_ * P_ * P_ * sizeof(unsigned short);  // + 38.5 MB

    psf_kernel<<<NPOS_, 1024, 0, stream>>>(w1, b1, w2, b2, w3, b3, basis, bfrags);

    int nPix = B_ * C_ * HW_ * HW_;
    if (ws_size >= need) {
        unsigned short* ypatch = (unsigned short*)((char*)d_ws + bfBytes);
        conv_mfma_kernel<0><<<BN_ * C_ * 2, 512, 0, stream>>>(x, bfrags, ypatch);
        gather_kernel<<<(nPix / 4 + 255) / 256, 256, 0, stream>>>(ypatch, out);
    } else {
        hipMemsetAsync(d_out, 0, (size_t)out_size * sizeof(float), stream);
        conv_mfma_kernel<1><<<BN_ * C_ * 2, 512, 0, stream>>>(x, bfrags, out);
        divide_kernel<<<(nPix + 255) / 256, 256, 0, stream>>>(out);
    }
}

// Round 10
// 80.145 us; speedup vs baseline: 1.2699x; 1.0746x over previous
//
#include <hip/hip_runtime.h>
#include <math.h>

#define B_ 8
#define C_ 3
#define HW_ 512
#define P_ 128
#define S_ 64
#define K_ 31
#define NZ_ 15
#define HID_ 64
#define NPOS_ 49   // 7x7 patch positions
#define BN_ (B_*NPOS_)

#define LSTRIDE_ 168   // bf16 elems/row; 336 B = 21 x 16B blocks (odd -> conflict-free b128)
#define TROWS_ 96      // 64-row half + 31 halo + 1 spare
#define FRAG_U32_ 256  // one B fragment = 64 lanes x 16 B = 256 uints
#define NSTEP_ 16      // 16 row-pair steps; jrow = 2s + (k>=16), jrow=0 masked (halo-16)
#define BPOS_U32_ (NSTEP_ * 3 * FRAG_U32_)  // 12288 uints per patch position

typedef __attribute__((ext_vector_type(8))) short bf16x8;
typedef __attribute__((ext_vector_type(4))) float f32x4;

__device__ __forceinline__ float hann128(int p) {
    return 0.5f - 0.5f * cosf(6.283185307179586f * (float)p / 128.0f);
}

__device__ __forceinline__ unsigned short bf16_rne(float f) {
    union { float f; unsigned int u; } v; v.f = f;
    unsigned int r = v.u + 0x7fffu + ((v.u >> 16) & 1u);
    return (unsigned short)(r >> 16);
}

__device__ __forceinline__ float bf16_to_f(unsigned int bits16) {
    union { unsigned int u; float f; } v; v.u = bits16 << 16;
    return v.f;
}

// ---------------------------------------------------------------------------
// Kernel 1: MLP + pupil + 31x31 DFT -> normalized flipped kernel -> row-pair
// B-fragment precompute (halo-16 convention). One block per position (49).
// Fragment (s, c), logical k in [0,32): jrow = 2s + (k>=16),
//   B_c[k][n] = kf[jrow-1, 16c + (k&15) - n - 1] if jrow,tap in 1..31 else 0.
// Lane labeling (matches conv A reads, empirically validated r4-r9):
//   lane l: n = l&15, k = (l>>4)*8 + e, e = 0..7.
// ---------------------------------------------------------------------------
__global__ __launch_bounds__(1024) void psf_kernel(
    const float* __restrict__ w1, const float* __restrict__ b1,
    const float* __restrict__ w2, const float* __restrict__ b2,
    const float* __restrict__ w3, const float* __restrict__ b3,
    const float* __restrict__ basis, unsigned int* __restrict__ bfrags)
{
    __shared__ float h1[HID_], h2[HID_], coef[NZ_];
    __shared__ float pupR[961], pupI[961], tR[961], tI[961];
    __shared__ float rootR[31], rootI[31];
    __shared__ float red[16];
    int n = blockIdx.x;
    int nh = n / 7, nw = n % 7;
    int tid = threadIdx.x;
    float cy = (float)(nh * S_ + P_ / 2) * (2.0f / (float)HW_) - 1.0f;
    float cx = (float)(nw * S_ + P_ / 2) * (2.0f / (float)HW_) - 1.0f;

    if (tid < HID_) h1[tid] = fmaxf(0.0f, cy * w1[tid] + cx * w1[HID_ + tid] + b1[tid]);
    if (tid < 31) {
        float ang = -6.283185307179586f * (float)tid / 31.0f;
        rootR[tid] = cosf(ang);
        rootI[tid] = sinf(ang);
    }
    __syncthreads();
    if (tid < HID_) {
        float s = b2[tid];
        for (int k = 0; k < HID_; ++k) s = fmaf(h1[k], w2[k * HID_ + tid], s);
        h2[tid] = fmaxf(0.0f, s);
    }
    __syncthreads();
    if (tid < NZ_) {
        float s = b3[tid];
        for (int k = 0; k < HID_; ++k) s = fmaf(h2[k], w3[k * NZ_ + tid], s);
        coef[tid] = s;
    }
    __syncthreads();

    for (int idx = tid; idx < 961; idx += 1024) {
        int h = idx / 31, w = idx % 31;
        float ph = 0.0f;
        for (int z = 0; z < NZ_; ++z) ph = fmaf(coef[z], basis[z * 961 + idx], ph);
        int dh = h - 15, dw = w - 15;
        bool m = (dh * dh + dw * dw) <= 225;
        float sv, cv;
        sincosf(ph, &sv, &cv);
        pupR[idx] = m ? cv : 0.0f;
        pupI[idx] = m ? sv : 0.0f;
    }
    __syncthreads();

    for (int idx = tid; idx < 961; idx += 1024) {
        int h = idx / 31, k = idx % 31;
        float ar = 0.0f, ai = 0.0f;
        for (int w = 0; w < 31; ++w) {
            int tt = (k * w) % 31;
            float cr = rootR[tt], ci = rootI[tt];
            float pr = pupR[h * 31 + w], pi = pupI[h * 31 + w];
            ar += pr * cr - pi * ci;
            ai += pr * ci + pi * cr;
        }
        tR[idx] = ar; tI[idx] = ai;
    }
    __syncthreads();

    float lsum = 0.0f;
    for (int idx = tid; idx < 961; idx += 1024) {
        int u = idx / 31, k = idx % 31;
        float gr = 0.0f, gi = 0.0f;
        for (int h = 0; h < 31; ++h) {
            int tt = (u * h) % 31;
            float cr = rootR[tt], ci = rootI[tt];
            float ar = tR[h * 31 + k], ai = tI[h * 31 + k];
            gr += ar * cr - ai * ci;
            gi += ar * ci + ai * cr;
        }
        float p = gr * gr + gi * gi;
        pupR[idx] = p;
        lsum += p;
    }
    float v = lsum;
    #pragma unroll
    for (int off = 32; off >= 1; off >>= 1) v += __shfl_xor(v, off, 64);
    if ((tid & 63) == 0) red[tid >> 6] = v;
    __syncthreads();
    if (tid == 0) {
        float s = 0.0f;
        #pragma unroll
        for (int i = 0; i < 16; ++i) s += red[i];
        red[0] = 1.0f / (s + 1e-12f);
    }
    __syncthreads();
    float inv = red[0];
    // kf[j,i] = psf_un[(15-j)%31, (15-i)%31] * inv  -> stash in tI (free now)
    for (int idx = tid; idx < 961; idx += 1024) {
        int j = idx / 31, i = idx % 31;
        int u = (15 - j + 31) % 31, vv = (15 - i + 31) % 31;
        tI[idx] = pupR[u * 31 + vv] * inv;
    }
    __syncthreads();

    unsigned int* bf = bfrags + (size_t)n * BPOS_U32_;
    for (int w2 = tid; w2 < BPOS_U32_; w2 += 1024) {
        int jc = w2 >> 8;            // 256 uints per fragment; jc = s*3 + c
        int s = jc / 3, c = jc % 3;
        int rem = w2 & 255;
        int l = rem >> 2, ew = rem & 3;
        int nn = l & 15, kg = l >> 4;
        unsigned int pack = 0;
        #pragma unroll
        for (int q = 0; q < 2; ++q) {
            int e = ew * 2 + q;
            int kk = kg * 8 + e;
            int jrow = 2 * s + (kk >> 4);          // halo-16: kernel row = jrow-1
            int tap = 16 * c + (kk & 15) - nn;     // halo-16: kernel col = tap-1
            float vx = (jrow >= 1 && jrow <= 31 && tap >= 1 && tap <= 31)
                       ? tI[(jrow - 1) * 31 + (tap - 1)] : 0.0f;
            pack |= (unsigned int)bf16_rne(vx) << (16 * q);
        }
        bf[w2] = pack;
    }
}

// ---------------------------------------------------------------------------
// Kernel 2 (v10): row-pair banded bf16 MFMA GEMM with FENCED 1-step pipeline.
// One block per (patch, channel, row-half): 64x128 out, 512 threads = 8 waves
// (4 row-strips x 2 col-halves). LDS tile 96x168 bf16, 32 KB.
// Fully-unrolled 16-step loop; per step: issue A(s+1)+B(s+1) loads, then
// sched_barrier(0) fence (stops the scheduler sinking loads past the MFMAs),
// then setprio(1) + 12 MFMA + setprio(0) + fence. Loads wait at NEXT step.
// ---------------------------------------------------------------------------
template<int MODE>
__global__ __launch_bounds__(512, 4) void conv_mfma_kernel(
    const float* __restrict__ x, const unsigned int* __restrict__ bfrags,
    void* __restrict__ dst)
{
    __shared__ unsigned short sIn[TROWS_ * LSTRIDE_];   // 96*168*2 = 32256 B
    __shared__ float sH[128];

    int t = blockIdx.x;
    int half = t & 1;
    int cc = (t >> 1) % 3;
    int bn = t / 6;
    int b = bn / NPOS_, n = bn % NPOS_;
    int nh = n / 7, nw = n % 7;
    int r0 = nh * S_, c0 = nw * S_;
    int tid = threadIdx.x;

    if (tid < 128) sH[tid] = hann128(tid);

    // zero-fill tile (halo + invalid rows stay zero)
    for (int i = tid; i < TROWS_ * LSTRIDE_ * 2 / 16; i += 512)
        ((uint4*)sIn)[i] = make_uint4(0u, 0u, 0u, 0u);
    __syncthreads();

    // stage interior: tile row r <-> patch row half*64 + r - 16; cols 16..143
    const float* xb = x + ((size_t)(b * C_ + cc) * HW_ + r0) * HW_ + c0;
    int rpbase = half * 64 - 16;
    for (int i = tid; i < TROWS_ * 32; i += 512) {
        int r = i >> 5, c4 = (i & 31) * 4;   // c4 = patch col 0,4,...,124
        int rp = rpbase + r;
        if (rp >= 0 && rp < P_) {
            float4 v = *(const float4*)&xb[rp * HW_ + c4];
            unsigned int lo = (unsigned int)bf16_rne(v.x) | ((unsigned int)bf16_rne(v.y) << 16);
            unsigned int hi = (unsigned int)bf16_rne(v.z) | ((unsigned int)bf16_rne(v.w) << 16);
            *(uint2*)&sIn[r * LSTRIDE_ + 16 + c4] = make_uint2(lo, hi);
        }
    }
    __syncthreads();

    int lane = tid & 63, wv = tid >> 6;
    int m0 = (wv & 3) * 16;        // row strip within the 64-row half
    int ch = (wv >> 2) * 64;       // col half
    int lrow = lane & 15, lkg = lane >> 4;

    f32x4 acc[4];
    #pragma unroll
    for (int q = 0; q < 4; ++q) acc[q] = (f32x4){0.f, 0.f, 0.f, 0.f};

    int abase = (m0 + lrow + (lkg >> 1)) * (LSTRIDE_ * 2) + ch * 2 + (lkg & 1) * 16;
    const char* ab = (const char*)sIn + abase;
    const bf16x8* bpos = (const bf16x8*)(bfrags + (size_t)n * BPOS_U32_) + lane;

    // prologue: load step 0
    bf16x8 Ac[6], Bc0, Bc1, Bc2;
    #pragma unroll
    for (int p = 0; p < 6; ++p) Ac[p] = *(const bf16x8*)(ab + p * 32);
    Bc0 = bpos[0]; Bc1 = bpos[64]; Bc2 = bpos[128];

    #pragma unroll
    for (int s = 0; s < NSTEP_; ++s) {
        bf16x8 An[6], Bn0, Bn1, Bn2;
        if (s + 1 < NSTEP_) {
            const char* ap = ab + 672 * (s + 1);   // 2 rows * 336 B per step
            #pragma unroll
            for (int p = 0; p < 6; ++p) An[p] = *(const bf16x8*)(ap + p * 32);
            const bf16x8* bnp = bpos + (s + 1) * 192;
            Bn0 = bnp[0]; Bn1 = bnp[64]; Bn2 = bnp[128];
        }
        __builtin_amdgcn_sched_barrier(0);     // pin load-issue above the MFMAs
        __builtin_amdgcn_s_setprio(1);
        #pragma unroll
        for (int q = 0; q < 4; ++q) {
            acc[q] = __builtin_amdgcn_mfma_f32_16x16x32_bf16(Ac[q],     Bc0, acc[q], 0, 0, 0);
            acc[q] = __builtin_amdgcn_mfma_f32_16x16x32_bf16(Ac[q + 1], Bc1, acc[q], 0, 0, 0);
            acc[q] = __builtin_amdgcn_mfma_f32_16x16x32_bf16(Ac[q + 2], Bc2, acc[q], 0, 0, 0);
        }
        __builtin_amdgcn_s_setprio(0);
        __builtin_amdgcn_sched_barrier(0);     // keep this step's MFMAs clustered
        if (s + 1 < NSTEP_) {
            #pragma unroll
            for (int p = 0; p < 6; ++p) Ac[p] = An[p];
            Bc0 = Bn0; Bc1 = Bn1; Bc2 = Bn2;
        }
    }

    // epilogue: C/D layout col = lane&15, row = lkg*4 + r (m89-verified)
    int prow0 = half * 64 + m0 + lkg * 4;
    float hy[4];
    #pragma unroll
    for (int r = 0; r < 4; ++r) hy[r] = sH[prow0 + r];

    #pragma unroll
    for (int q = 0; q < 4; ++q) {
        int pcol = ch + 16 * q + lrow;
        float hxv = sH[pcol];
        #pragma unroll
        for (int r = 0; r < 4; ++r) {
            int prow = prow0 + r;
            float val = acc[q][r] * hy[r] * hxv;
            if (MODE == 0) {
                unsigned short* yp = (unsigned short*)dst + (((size_t)bn * C_ + cc) << 14);
                yp[prow * P_ + pcol] = bf16_rne(val);
            } else {
                float* ob = (float*)dst;
                atomicAdd(ob + ((size_t)(b * C_ + cc) * HW_ + r0 + prow) * HW_ + c0 + pcol, val);
            }
        }
    }
}

// ---------------------------------------------------------------------------
// Kernel 3a: gather overlap-add (x4 vectorized, bf16 patches), analytic divide
// ---------------------------------------------------------------------------
__global__ __launch_bounds__(256) void gather_kernel(
    const unsigned short* __restrict__ ypatch, float* __restrict__ out)
{
    __shared__ float sH[128];
    int tid = threadIdx.x;
    if (tid < 128) sH[tid] = hann128(tid);
    __syncthreads();

    int gid = blockIdx.x * 256 + tid;
    int base = gid * 4;
    if (base >= B_ * C_ * HW_ * HW_) return;
    int X = base & 511;
    int Y = (base >> 9) & 511;
    int bc = base >> 18;
    int c = bc % 3, b = bc / 3;
    int nhA = Y >> 6, pyA = Y & 63;
    int nwA = X >> 6, pxA = X & 63;       // multiple of 4
    bool vA = nhA <= 6, vB = nhA >= 1;
    bool uA = nwA <= 6, uB = nwA >= 1;
    float wy = (vA ? sH[pyA] : 0.0f) + (vB ? sH[pyA + 64] : 0.0f);

    float4 acc = {0.f, 0.f, 0.f, 0.f};
    #pragma unroll
    for (int sy = 0; sy < 2; ++sy) {
        bool okY = sy == 0 ? vA : vB;
        int nh = sy == 0 ? nhA : nhA - 1;
        int py = sy == 0 ? pyA : pyA + 64;
        #pragma unroll
        for (int sx = 0; sx < 2; ++sx) {
            bool okX = sx == 0 ? uA : uB;
            int nw = sx == 0 ? nwA : nwA - 1;
            int px = sx == 0 ? pxA : pxA + 64;
            if (okY && okX) {
                size_t off = ((((size_t)b * NPOS_ + nh * 7 + nw) * C_ + c) << 14) + (py << 7) + px;
                uint2 v = *(const uint2*)&ypatch[off];
                acc.x += bf16_to_f(v.x & 0xffffu);
                acc.y += bf16_to_f(v.x >> 16);
                acc.z += bf16_to_f(v.y & 0xffffu);
                acc.w += bf16_to_f(v.y >> 16);
            }
        }
    }
    float4 o;
    float wx0 = (uA ? sH[pxA + 0] : 0.0f) + (uB ? sH[pxA + 64] : 0.0f);
    float wx1 = (uA ? sH[pxA + 1] : 0.0f) + (uB ? sH[pxA + 65] : 0.0f);
    float wx2 = (uA ? sH[pxA + 2] : 0.0f) + (uB ? sH[pxA + 66] : 0.0f);
    float wx3 = (uA ? sH[pxA + 3] : 0.0f) + (uB ? sH[pxA + 67] : 0.0f);
    o.x = acc.x / (wy * wx0 + 1e-8f);
    o.y = acc.y / (wy * wx1 + 1e-8f);
    o.z = acc.z / (wy * wx2 + 1e-8f);
    o.w = acc.w / (wy * wx3 + 1e-8f);
    *(float4*)&out[base] = o;
}

// ---------------------------------------------------------------------------
// Kernel 3b: in-place divide (atomic fallback path)
// ---------------------------------------------------------------------------
__global__ __launch_bounds__(256) void divide_kernel(float* __restrict__ out)
{
    int idx = blockIdx.x * 256 + threadIdx.x;
    if (idx >= B_ * C_ * HW_ * HW_) return;
    int X = idx & 511;
    int Y = (idx >> 9) & 511;
    int nhA = Y >> 6, pyA = Y & 63;
    int nwA = X >> 6, pxA = X & 63;
    float wy = (nhA <= 6 ? hann128(pyA) : 0.0f) + (nhA >= 1 ? hann128(pyA + 64) : 0.0f);
    float wx = (nwA <= 6 ? hann128(pxA) : 0.0f) + (nwA >= 1 ? hann128(pxA + 64) : 0.0f);
    out[idx] = out[idx] / (wy * wx + 1e-8f);
}

extern "C" void kernel_launch(void* const* d_in, const int* in_sizes, int n_in,
                              void* d_out, int out_size, void* d_ws, size_t ws_size,
                              hipStream_t stream)
{
    const float* x    = (const float*)d_in[0];
    const float* w1   = (const float*)d_in[1];
    const float* b1   = (const float*)d_in[2];
    const float* w2   = (const float*)d_in[3];
    const float* b2   = (const float*)d_in[4];
    const float* w3   = (const float*)d_in[5];
    const float* b3   = (const float*)d_in[6];
    const float* basis = (const float*)d_in[7];
    float* out = (float*)d_out;

    unsigned int* bfrags = (unsigned int*)d_ws;
    size_t bfBytes = (size_t)NPOS_ * BPOS_U32_ * sizeof(unsigned int);            // ~2.41 MB
    size_t need = bfBytes + (size_t)BN_ * C_ * P_ * P_ * sizeof(unsigned short);  // + 38.5 MB

    psf_kernel<<<NPOS_, 1024, 0, stream>>>(w1, b1, w2, b2, w3, b3, basis, bfrags);

    int nPix = B_ * C_ * HW_ * HW_;
    if (ws_size >= need) {
        unsigned short* ypatch = (unsigned short*)((char*)d_ws + bfBytes);
        conv_mfma_kernel<0><<<BN_ * C_ * 2, 512, 0, stream>>>(x, bfrags, ypatch);
        gather_kernel<<<(nPix / 4 + 255) / 256, 256, 0, stream>>>(ypatch, out);
    } else {
        hipMemsetAsync(d_out, 0, (size_t)out_size * sizeof(float), stream);
        conv_mfma_kernel<1><<<BN_ * C_ * 2, 512, 0, stream>>>(x, bfrags, out);
        divide_kernel<<<(nPix + 255) / 256, 256, 0, stream>>>(out);
    }
}

// Round 11
// 79.871 us; speedup vs baseline: 1.2743x; 1.0034x over previous
//
#include <hip/hip_runtime.h>
#include <math.h>

#define B_ 8
#define C_ 3
#define HW_ 512
#define P_ 128
#define S_ 64
#define K_ 31
#define NZ_ 15
#define HID_ 64
#define NPOS_ 49   // 7x7 patch positions
#define BN_ (B_*NPOS_)

#define LSTRIDE_ 168   // bf16 elems/row; 336 B = 21 x 16B blocks (odd -> conflict-free b128)
#define TROWS_ 96      // 64-row half + 31 halo + 1 spare
#define FRAG_U32_ 256  // one B fragment = 64 lanes x 16 B = 256 uints
#define NSTEP_ 16      // 16 row-pair steps; jrow = 2s + (k>=16), jrow=0 masked (halo-16)
#define BPOS_U32_ (NSTEP_ * 3 * FRAG_U32_)  // 12288 uints per patch position

typedef __attribute__((ext_vector_type(8))) short bf16x8;
typedef __attribute__((ext_vector_type(4))) float f32x4;

__device__ __forceinline__ float hann128(int p) {
    return 0.5f - 0.5f * cosf(6.283185307179586f * (float)p / 128.0f);
}

__device__ __forceinline__ unsigned int bf16_rne(float f) {
    union { float f; unsigned int u; } v; v.f = f;
    unsigned int r = v.u + 0x7fffu + ((v.u >> 16) & 1u);
    return r >> 16;
}

__device__ __forceinline__ float bf16_to_f(unsigned int bits16) {
    union { unsigned int u; float f; } v; v.u = bits16 << 16;
    return v.f;
}

// ---------------------------------------------------------------------------
// Kernel 1: MLP + pupil + 31x31 DFT -> normalized flipped kernel -> row-pair
// B-fragment precompute (halo-16 convention). One block per position (49).
// Fragment (s, c), logical k in [0,32): jrow = 2s + (k>=16),
//   B_c[k][n] = kf[jrow-1, 16c + (k&15) - n - 1] if jrow,tap in 1..31 else 0.
// Lane labeling (matches conv A reads, empirically validated r4-r10):
//   lane l: n = l&15, k = (l>>4)*8 + e, e = 0..7.
// ---------------------------------------------------------------------------
__global__ __launch_bounds__(1024) void psf_kernel(
    const float* __restrict__ w1, const float* __restrict__ b1,
    const float* __restrict__ w2, const float* __restrict__ b2,
    const float* __restrict__ w3, const float* __restrict__ b3,
    const float* __restrict__ basis, unsigned int* __restrict__ bfrags)
{
    __shared__ float h1[HID_], h2[HID_], coef[NZ_];
    __shared__ float pupR[961], pupI[961], tR[961], tI[961];
    __shared__ float rootR[31], rootI[31];
    __shared__ float red[16];
    int n = blockIdx.x;
    int nh = n / 7, nw = n % 7;
    int tid = threadIdx.x;
    float cy = (float)(nh * S_ + P_ / 2) * (2.0f / (float)HW_) - 1.0f;
    float cx = (float)(nw * S_ + P_ / 2) * (2.0f / (float)HW_) - 1.0f;

    if (tid < HID_) h1[tid] = fmaxf(0.0f, cy * w1[tid] + cx * w1[HID_ + tid] + b1[tid]);
    if (tid < 31) {
        float ang = -6.283185307179586f * (float)tid / 31.0f;
        rootR[tid] = cosf(ang);
        rootI[tid] = sinf(ang);
    }
    __syncthreads();
    if (tid < HID_) {
        float s = b2[tid];
        for (int k = 0; k < HID_; ++k) s = fmaf(h1[k], w2[k * HID_ + tid], s);
        h2[tid] = fmaxf(0.0f, s);
    }
    __syncthreads();
    if (tid < NZ_) {
        float s = b3[tid];
        for (int k = 0; k < HID_; ++k) s = fmaf(h2[k], w3[k * NZ_ + tid], s);
        coef[tid] = s;
    }
    __syncthreads();

    for (int idx = tid; idx < 961; idx += 1024) {
        int h = idx / 31, w = idx % 31;
        float ph = 0.0f;
        for (int z = 0; z < NZ_; ++z) ph = fmaf(coef[z], basis[z * 961 + idx], ph);
        int dh = h - 15, dw = w - 15;
        bool m = (dh * dh + dw * dw) <= 225;
        float sv, cv;
        sincosf(ph, &sv, &cv);
        pupR[idx] = m ? cv : 0.0f;
        pupI[idx] = m ? sv : 0.0f;
    }
    __syncthreads();

    for (int idx = tid; idx < 961; idx += 1024) {
        int h = idx / 31, k = idx % 31;
        float ar = 0.0f, ai = 0.0f;
        for (int w = 0; w < 31; ++w) {
            int tt = (k * w) % 31;
            float cr = rootR[tt], ci = rootI[tt];
            float pr = pupR[h * 31 + w], pi = pupI[h * 31 + w];
            ar += pr * cr - pi * ci;
            ai += pr * ci + pi * cr;
        }
        tR[idx] = ar; tI[idx] = ai;
    }
    __syncthreads();

    float lsum = 0.0f;
    for (int idx = tid; idx < 961; idx += 1024) {
        int u = idx / 31, k = idx % 31;
        float gr = 0.0f, gi = 0.0f;
        for (int h = 0; h < 31; ++h) {
            int tt = (u * h) % 31;
            float cr = rootR[tt], ci = rootI[tt];
            float ar = tR[h * 31 + k], ai = tI[h * 31 + k];
            gr += ar * cr - ai * ci;
            gi += ar * ci + ai * cr;
        }
        float p = gr * gr + gi * gi;
        pupR[idx] = p;
        lsum += p;
    }
    float v = lsum;
    #pragma unroll
    for (int off = 32; off >= 1; off >>= 1) v += __shfl_xor(v, off, 64);
    if ((tid & 63) == 0) red[tid >> 6] = v;
    __syncthreads();
    if (tid == 0) {
        float s = 0.0f;
        #pragma unroll
        for (int i = 0; i < 16; ++i) s += red[i];
        red[0] = 1.0f / (s + 1e-12f);
    }
    __syncthreads();
    float inv = red[0];
    // kf[j,i] = psf_un[(15-j)%31, (15-i)%31] * inv  -> stash in tI (free now)
    for (int idx = tid; idx < 961; idx += 1024) {
        int j = idx / 31, i = idx % 31;
        int u = (15 - j + 31) % 31, vv = (15 - i + 31) % 31;
        tI[idx] = pupR[u * 31 + vv] * inv;
    }
    __syncthreads();

    unsigned int* bf = bfrags + (size_t)n * BPOS_U32_;
    for (int w2 = tid; w2 < BPOS_U32_; w2 += 1024) {
        int jc = w2 >> 8;            // 256 uints per fragment; jc = s*3 + c
        int s = jc / 3, c = jc % 3;
        int rem = w2 & 255;
        int l = rem >> 2, ew = rem & 3;
        int nn = l & 15, kg = l >> 4;
        unsigned int pack = 0;
        #pragma unroll
        for (int q = 0; q < 2; ++q) {
            int e = ew * 2 + q;
            int kk = kg * 8 + e;
            int jrow = 2 * s + (kk >> 4);          // halo-16: kernel row = jrow-1
            int tap = 16 * c + (kk & 15) - nn;     // halo-16: kernel col = tap-1
            float vx = (jrow >= 1 && jrow <= 31 && tap >= 1 && tap <= 31)
                       ? tI[(jrow - 1) * 31 + (tap - 1)] : 0.0f;
            pack |= bf16_rne(vx) << (16 * q);
        }
        bf[w2] = pack;
    }
}

// ---------------------------------------------------------------------------
// Kernel 2 (v11): row-pair banded bf16 MFMA GEMM, FORCED ping-pong pipeline.
// One block per (patch, channel, row-half): 64x128 out, 512 threads = 8 waves
// (4 row-strips x 2 col-halves). LDS tile 96x168 bf16, 32 KB, 2 blocks/CU.
// Explicit A0/A1, B0/B1 double buffers with compile-time parity (no copies,
// so the loads are dataflow-live across the MFMA region and CANNOT be sunk
// by the scheduler or coalesced by RA). Fences + setprio around each
// 12-MFMA cluster. Staging uses uint4 ds_writes (conflict-minimal).
// ---------------------------------------------------------------------------
template<int MODE>
__global__ __launch_bounds__(512, 4) void conv_mfma_kernel(
    const float* __restrict__ x, const unsigned int* __restrict__ bfrags,
    void* __restrict__ dst)
{
    __shared__ unsigned short sIn[TROWS_ * LSTRIDE_];   // 96*168*2 = 32256 B
    __shared__ float sH[128];

    int t = blockIdx.x;
    int half = t & 1;
    int cc = (t >> 1) % 3;
    int bn = t / 6;
    int b = bn / NPOS_, n = bn % NPOS_;
    int nh = n / 7, nw = n % 7;
    int r0 = nh * S_, c0 = nw * S_;
    int tid = threadIdx.x;

    if (tid < 128) sH[tid] = hann128(tid);

    // zero-fill tile (halo + invalid rows stay zero)
    for (int i = tid; i < TROWS_ * LSTRIDE_ * 2 / 16; i += 512)
        ((uint4*)sIn)[i] = make_uint4(0u, 0u, 0u, 0u);
    __syncthreads();

    // stage interior with uint4 writes: tile row r <-> patch row half*64+r-16
    const float* xb = x + ((size_t)(b * C_ + cc) * HW_ + r0) * HW_ + c0;
    int rpbase = half * 64 - 16;
    for (int i = tid; i < TROWS_ * 16; i += 512) {
        int r = i >> 4, c8 = (i & 15) * 8;   // patch cols c8..c8+7
        int rp = rpbase + r;
        if (rp >= 0 && rp < P_) {
            float4 v0 = *(const float4*)&xb[rp * HW_ + c8];
            float4 v1 = *(const float4*)&xb[rp * HW_ + c8 + 4];
            uint4 o;
            o.x = bf16_rne(v0.x) | (bf16_rne(v0.y) << 16);
            o.y = bf16_rne(v0.z) | (bf16_rne(v0.w) << 16);
            o.z = bf16_rne(v1.x) | (bf16_rne(v1.y) << 16);
            o.w = bf16_rne(v1.z) | (bf16_rne(v1.w) << 16);
            *(uint4*)&sIn[r * LSTRIDE_ + 16 + c8] = o;
        }
    }
    __syncthreads();

    int lane = tid & 63, wv = tid >> 6;
    int m0 = (wv & 3) * 16;        // row strip within the 64-row half
    int ch = (wv >> 2) * 64;       // col half
    int lrow = lane & 15, lkg = lane >> 4;

    f32x4 acc[4];
    #pragma unroll
    for (int q = 0; q < 4; ++q) acc[q] = (f32x4){0.f, 0.f, 0.f, 0.f};

    int abase = (m0 + lrow + (lkg >> 1)) * (LSTRIDE_ * 2) + ch * 2 + (lkg & 1) * 16;
    const char* ab = (const char*)sIn + abase;
    const bf16x8* bpos = (const bf16x8*)(bfrags + (size_t)n * BPOS_U32_) + lane;

    bf16x8 A0[6], A1[6], B0[3], B1[3];

#define LOADA(DST, S) { const char* ap_ = ab + 672 * (S); \
    _Pragma("unroll") for (int p_ = 0; p_ < 6; ++p_) DST[p_] = *(const bf16x8*)(ap_ + p_ * 32); }
#define LOADB(DST, S) { const bf16x8* bp_ = bpos + (S) * 192; \
    DST[0] = bp_[0]; DST[1] = bp_[64]; DST[2] = bp_[128]; }
#define DOMFMA(AA, BB) { _Pragma("unroll") for (int q_ = 0; q_ < 4; ++q_) { \
    acc[q_] = __builtin_amdgcn_mfma_f32_16x16x32_bf16(AA[q_],     BB[0], acc[q_], 0, 0, 0); \
    acc[q_] = __builtin_amdgcn_mfma_f32_16x16x32_bf16(AA[q_ + 1], BB[1], acc[q_], 0, 0, 0); \
    acc[q_] = __builtin_amdgcn_mfma_f32_16x16x32_bf16(AA[q_ + 2], BB[2], acc[q_], 0, 0, 0); } }

    LOADA(A0, 0); LOADB(B0, 0);

    #pragma unroll
    for (int s2 = 0; s2 < 8; ++s2) {
        // prefetch odd step into buffer 1 (live across the MFMA below)
        LOADA(A1, 2 * s2 + 1); LOADB(B1, 2 * s2 + 1);
        __builtin_amdgcn_sched_barrier(0);
        __builtin_amdgcn_s_setprio(1);
        DOMFMA(A0, B0);
        __builtin_amdgcn_s_setprio(0);
        __builtin_amdgcn_sched_barrier(0);
        // prefetch next even step into buffer 0
        if (s2 < 7) { LOADA(A0, 2 * s2 + 2); LOADB(B0, 2 * s2 + 2); }
        __builtin_amdgcn_sched_barrier(0);
        __builtin_amdgcn_s_setprio(1);
        DOMFMA(A1, B1);
        __builtin_amdgcn_s_setprio(0);
        __builtin_amdgcn_sched_barrier(0);
    }
#undef LOADA
#undef LOADB
#undef DOMFMA

    // epilogue: C/D layout col = lane&15, row = lkg*4 + r (m89-verified)
    int prow0 = half * 64 + m0 + lkg * 4;
    float hy[4];
    #pragma unroll
    for (int r = 0; r < 4; ++r) hy[r] = sH[prow0 + r];

    #pragma unroll
    for (int q = 0; q < 4; ++q) {
        int pcol = ch + 16 * q + lrow;
        float hxv = sH[pcol];
        #pragma unroll
        for (int r = 0; r < 4; ++r) {
            int prow = prow0 + r;
            float val = acc[q][r] * hy[r] * hxv;
            if (MODE == 0) {
                unsigned short* yp = (unsigned short*)dst + (((size_t)bn * C_ + cc) << 14);
                yp[prow * P_ + pcol] = (unsigned short)bf16_rne(val);
            } else {
                float* ob = (float*)dst;
                atomicAdd(ob + ((size_t)(b * C_ + cc) * HW_ + r0 + prow) * HW_ + c0 + pcol, val);
            }
        }
    }
}

// ---------------------------------------------------------------------------
// Kernel 3a: gather overlap-add (x4 vectorized, bf16 patches), analytic divide
// ---------------------------------------------------------------------------
__global__ __launch_bounds__(256) void gather_kernel(
    const unsigned short* __restrict__ ypatch, float* __restrict__ out)
{
    __shared__ float sH[128];
    int tid = threadIdx.x;
    if (tid < 128) sH[tid] = hann128(tid);
    __syncthreads();

    int gid = blockIdx.x * 256 + tid;
    int base = gid * 4;
    if (base >= B_ * C_ * HW_ * HW_) return;
    int X = base & 511;
    int Y = (base >> 9) & 511;
    int bc = base >> 18;
    int c = bc % 3, b = bc / 3;
    int nhA = Y >> 6, pyA = Y & 63;
    int nwA = X >> 6, pxA = X & 63;       // multiple of 4
    bool vA = nhA <= 6, vB = nhA >= 1;
    bool uA = nwA <= 6, uB = nwA >= 1;
    float wy = (vA ? sH[pyA] : 0.0f) + (vB ? sH[pyA + 64] : 0.0f);

    float4 acc = {0.f, 0.f, 0.f, 0.f};
    #pragma unroll
    for (int sy = 0; sy < 2; ++sy) {
        bool okY = sy == 0 ? vA : vB;
        int nh = sy == 0 ? nhA : nhA - 1;
        int py = sy == 0 ? pyA : pyA + 64;
        #pragma unroll
        for (int sx = 0; sx < 2; ++sx) {
            bool okX = sx == 0 ? uA : uB;
            int nw = sx == 0 ? nwA : nwA - 1;
            int px = sx == 0 ? pxA : pxA + 64;
            if (okY && okX) {
                size_t off = ((((size_t)b * NPOS_ + nh * 7 + nw) * C_ + c) << 14) + (py << 7) + px;
                uint2 v = *(const uint2*)&ypatch[off];
                acc.x += bf16_to_f(v.x & 0xffffu);
                acc.y += bf16_to_f(v.x >> 16);
                acc.z += bf16_to_f(v.y & 0xffffu);
                acc.w += bf16_to_f(v.y >> 16);
            }
        }
    }
    float4 o;
    float wx0 = (uA ? sH[pxA + 0] : 0.0f) + (uB ? sH[pxA + 64] : 0.0f);
    float wx1 = (uA ? sH[pxA + 1] : 0.0f) + (uB ? sH[pxA + 65] : 0.0f);
    float wx2 = (uA ? sH[pxA + 2] : 0.0f) + (uB ? sH[pxA + 66] : 0.0f);
    float wx3 = (uA ? sH[pxA + 3] : 0.0f) + (uB ? sH[pxA + 67] : 0.0f);
    o.x = acc.x / (wy * wx0 + 1e-8f);
    o.y = acc.y / (wy * wx1 + 1e-8f);
    o.z = acc.z / (wy * wx2 + 1e-8f);
    o.w = acc.w / (wy * wx3 + 1e-8f);
    *(float4*)&out[base] = o;
}

// ---------------------------------------------------------------------------
// Kernel 3b: in-place divide (atomic fallback path)
// ---------------------------------------------------------------------------
__global__ __launch_bounds__(256) void divide_kernel(float* __restrict__ out)
{
    int idx = blockIdx.x * 256 + threadIdx.x;
    if (idx >= B_ * C_ * HW_ * HW_) return;
    int X = idx & 511;
    int Y = (idx >> 9) & 511;
    int nhA = Y >> 6, pyA = Y & 63;
    int nwA = X >> 6, pxA = X & 63;
    float wy = (nhA <= 6 ? hann128(pyA) : 0.0f) + (nhA >= 1 ? hann128(pyA + 64) : 0.0f);
    float wx = (nwA <= 6 ? hann128(pxA) : 0.0f) + (nwA >= 1 ? hann128(pxA + 64) : 0.0f);
    out[idx] = out[idx] / (wy * wx + 1e-8f);
}

extern "C" void kernel_launch(void* const* d_in, const int* in_sizes, int n_in,
                              void* d_out, int out_size, void* d_ws, size_t ws_size,
                              hipStream_t stream)
{
    const float* x    = (const float*)d_in[0];
    const float* w1   = (const float*)d_in[1];
    const float* b1   = (const float*)d_in[2];
    const float* w2   = (const float*)d_in[3];
    const float* b2   = (const float*)d_in[4];
    const float* w3   = (const float*)d_in[5];
    const float* b3   = (const float*)d_in[6];
    const float* basis = (const float*)d_in[7];
    float* out = (float*)d_out;

    unsigned int* bfrags = (unsigned int*)d_ws;
    size_t bfBytes = (size_t)NPOS_ * BPOS_U32_ * sizeof(unsigned int);            // ~2.41 MB
    size_t need = bfBytes + (size_t)BN_ * C_ * P_ * P_ * sizeof(unsigned short);  // + 38.5 MB

    psf_kernel<<<NPOS_, 1024, 0, stream>>>(w1, b1, w2, b2, w3, b3, basis, bfrags);

    int nPix = B_ * C_ * HW_ * HW_;
    if (ws_size >= need) {
        unsigned short* ypatch = (unsigned short*)((char*)d_ws + bfBytes);
        conv_mfma_kernel<0><<<BN_ * C_ * 2, 512, 0, stream>>>(x, bfrags, ypatch);
        gather_kernel<<<(nPix / 4 + 255) / 256, 256, 0, stream>>>(ypatch, out);
    } else {
        hipMemsetAsync(d_out, 0, (size_t)out_size * sizeof(float), stream);
        conv_mfma_kernel<1><<<BN_ * C_ * 2, 512, 0, stream>>>(x, bfrags, out);
        divide_kernel<<<(nPix + 255) / 256, 256, 0, stream>>>(out);
    }
}